// Round 11
// baseline (785.606 us; speedup 1.0000x reference)
//
#include <hip/hip_runtime.h>
#include <hip/hip_bf16.h>
#include <math.h>

// Problem constants
#define BB 16
#define QQ 100
#define NH 8
#define HWN 4096
#define NORM_FACT 0.17677669529663687f   // 32^-0.5
#define QPAD 112        // q rows padded to 112 (7 tiles of 16)
#define NSLOT 2048      // partial slots per (b,q): 64 hwblocks * 4 waves * 8 heads

typedef short bf16x8_t __attribute__((ext_vector_type(8)));
typedef float f32x4_t  __attribute__((ext_vector_type(4)));

__device__ __forceinline__ unsigned short bf16bits(float f) {
    __hip_bfloat16 h = __float2bfloat16(f);           // RNE
    return __builtin_bit_cast(unsigned short, h);
}
__device__ __forceinline__ float bf16tof(unsigned short u) {
    union { unsigned int i; float f; } x; x.i = (unsigned int)u << 16; return x.f;
}

// ---------------- K0: WqT (fp32 transpose) + Wk -> bf16 -----------------------
__global__ void k_prep(const float* __restrict__ Wq, const float* __restrict__ Wk,
                       float* __restrict__ WqT, unsigned short* __restrict__ Wkbf) {
    int idx = blockIdx.x;
    int h = threadIdx.x;
    if (idx < 256) {
        WqT[idx * 256 + h] = Wq[h * 256 + idx];
    } else {
        int r = idx - 256;
        Wkbf[r * 256 + h] = bf16bits(Wk[r * 256 + h]);
    }
}

// ---------------- K1: q-proj -> bf16 hi/lo split, padded to 112 rows ----------
__global__ __launch_bounds__(256) void k_qproj(const float* __restrict__ q,
                                               const float* __restrict__ WqT,
                                               const float* __restrict__ bq,
                                               unsigned short* __restrict__ qphi,
                                               unsigned short* __restrict__ qplo) {
    int blk = blockIdx.x;             // 16 b x 28 tiles of 4 rows
    int b = blk / 28, q0 = (blk % 28) * 4;
    int h = threadIdx.x;
    size_t obase = ((size_t)b * QPAD + q0) * 256 + h;
    if (q0 >= QQ) {                   // padding rows -> zeros
#pragma unroll
        for (int i = 0; i < 4; ++i) { qphi[obase + i * 256] = 0; qplo[obase + i * 256] = 0; }
        return;
    }
    __shared__ float qsh[4][256];
    int ibase = (b * QQ + q0) * 256;
#pragma unroll
    for (int i = 0; i < 4; ++i) qsh[i][h] = q[ibase + i * 256 + h];
    __syncthreads();
    float bias = bq[h];
    float a0 = bias, a1 = bias, a2 = bias, a3 = bias;
    for (int c = 0; c < 256; ++c) {
        float wv = WqT[c * 256 + h];
        a0 = fmaf(qsh[0][c], wv, a0);
        a1 = fmaf(qsh[1][c], wv, a1);
        a2 = fmaf(qsh[2][c], wv, a2);
        a3 = fmaf(qsh[3][c], wv, a3);
    }
    float a[4] = {a0 * NORM_FACT, a1 * NORM_FACT, a2 * NORM_FACT, a3 * NORM_FACT};
#pragma unroll
    for (int i = 0; i < 4; ++i) {
        unsigned short hi = bf16bits(a[i]);
        qphi[obase + i * 256] = hi;
        qplo[obase + i * 256] = bf16bits(a[i] - bf16tof(hi));
    }
}

// ---------------- K2: fused transpose+kproj (DIAGNOSTIC: reps) ----------------
__global__ __launch_bounds__(512) void k_kproj3(const float* __restrict__ k,
                                                const unsigned short* __restrict__ Wkbf,
                                                const float* __restrict__ bk,
                                                unsigned short* __restrict__ kpT,
                                                int reps) {
    int b = blockIdx.y;
    int hwblk = blockIdx.x * 64;
    int t = threadIdx.x;
    int w = t >> 6, lane = t & 63;
    int hwt = w & 3, oh = w >> 2;
    int n15 = lane & 15, kg = lane >> 4;
    int hw_l = hwt * 16 + n15;

    __shared__ float lds_f[64][140];

#pragma unroll 1
    for (int rep = 0; rep < reps; ++rep) {
        int off0 = 0; asm volatile("" : "+v"(off0));   // opaque 0
        __syncthreads();

        f32x4_t acc[8];
#pragma unroll
        for (int m = 0; m < 8; ++m) acc[m] = f32x4_t{0.f, 0.f, 0.f, 0.f};

        const float* kb = k + (size_t)b * 256 * HWN + hwblk + off0;
        const unsigned short* wbase = Wkbf + ((size_t)(oh * 128 + n15)) * 256 + kg * 8 + off0;
        int c_l = t >> 4, l16 = t & 15;

#pragma unroll
        for (int chunk = 0; chunk < 2; ++chunk) {
#pragma unroll
            for (int p = 0; p < 4; ++p) {
                int cc = p * 32 + c_l;
                float4 v = *(const float4*)(kb + (size_t)(chunk * 128 + cc) * HWN + l16 * 4);
                lds_f[l16 * 4 + 0][cc] = v.x;
                lds_f[l16 * 4 + 1][cc] = v.y;
                lds_f[l16 * 4 + 2][cc] = v.z;
                lds_f[l16 * 4 + 3][cc] = v.w;
            }
            __syncthreads();
#pragma unroll
            for (int ksl = 0; ksl < 4; ++ksl) {
                f32x4_t f0 = *(const f32x4_t*)&lds_f[hw_l][ksl * 32 + kg * 8];
                f32x4_t f1 = *(const f32x4_t*)&lds_f[hw_l][ksl * 32 + kg * 8 + 4];
                bf16x8_t bfrag;
#pragma unroll
                for (int j = 0; j < 4; ++j) {
                    bfrag[j]     = (short)bf16bits(f0[j]);
                    bfrag[4 + j] = (short)bf16bits(f1[j]);
                }
                int ks = chunk * 4 + ksl;
#pragma unroll
                for (int m = 0; m < 8; ++m) {
                    bf16x8_t afrag = *reinterpret_cast<const bf16x8_t*>(wbase + (size_t)m * 16 * 256 + ks * 32);
                    acc[m] = __builtin_amdgcn_mfma_f32_16x16x32_bf16(afrag, bfrag, acc[m], 0, 0, 0);
                }
            }
            __syncthreads();
        }

        unsigned short* tile2 = (unsigned short*)lds_f;
#pragma unroll
        for (int m = 0; m < 8; ++m) {
            ushort4 pk;
            unsigned short* pkp = (unsigned short*)&pk;
#pragma unroll
            for (int r = 0; r < 4; ++r) {
                int o = oh * 128 + m * 16 + kg * 4 + r;
                pkp[r] = bf16bits(acc[m][r] + bk[o]);
            }
            *(ushort4*)&tile2[(size_t)hw_l * 264 + oh * 128 + m * 16 + kg * 4] = pk;
        }
        __syncthreads();
        int l5 = t & 31;
#pragma unroll
        for (int it = 0; it < 4; ++it) {
            int row = it * 16 + (t >> 5);
            uint4 v = *(const uint4*)&tile2[(size_t)row * 264 + l5 * 8];
            *(uint4*)(kpT + ((size_t)b * HWN + hwblk + row) * 256 + l5 * 8 + off0) = v;
        }
    }
}

// ---------------- K3: sum-pass, head-split (DIAGNOSTIC: reps) -----------------
__global__ __launch_bounds__(256) void k_sums(const unsigned short* __restrict__ qphi,
                                              const unsigned short* __restrict__ qplo,
                                              const unsigned short* __restrict__ kpT,
                                              const int* __restrict__ mask,
                                              float* __restrict__ partial,
                                              int reps) {
    int hwb = blockIdx.x, n = blockIdx.y, b = blockIdx.z;
    int t = threadIdx.x, w = t >> 6, lane = t & 63;
    int n15 = lane & 15, kg = lane >> 4;
    int hw = hwb * 64 + w * 16 + n15;
    float mm = mask[b * HWN + hw] ? 0.0f : 1.0f;
    int slot = (hwb * 4 + w) * 8 + n;
#pragma unroll 1
    for (int rep = 0; rep < reps; ++rep) {
        int off0 = 0; asm volatile("" : "+v"(off0));
        bf16x8_t bfr = *reinterpret_cast<const bf16x8_t*>(
            kpT + ((size_t)(b * HWN + hw)) * 256 + n * 32 + kg * 8 + off0);
        const unsigned short* ahi_b = qphi + ((size_t)(b * QPAD + n15)) * 256 + n * 32 + kg * 8 + off0;
        const unsigned short* alo_b = qplo + ((size_t)(b * QPAD + n15)) * 256 + n * 32 + kg * 8 + off0;
        float* pbase = partial + (size_t)b * QPAD * NSLOT + slot;
#pragma unroll
        for (int mt = 0; mt < 7; ++mt) {
            bf16x8_t ahi = *reinterpret_cast<const bf16x8_t*>(ahi_b + (size_t)(mt * 16) * 256);
            bf16x8_t alo = *reinterpret_cast<const bf16x8_t*>(alo_b + (size_t)(mt * 16) * 256);
            f32x4_t a2 = {0.f, 0.f, 0.f, 0.f};
            a2 = __builtin_amdgcn_mfma_f32_16x16x32_bf16(ahi, bfr, a2, 0, 0, 0);
            a2 = __builtin_amdgcn_mfma_f32_16x16x32_bf16(alo, bfr, a2, 0, 0, 0);
#pragma unroll
            for (int r = 0; r < 4; ++r) {
                float v = __expf(a2[r]) * mm;
                v += __shfl_xor(v, 1, 64);
                v += __shfl_xor(v, 2, 64);
                v += __shfl_xor(v, 4, 64);
                v += __shfl_xor(v, 8, 64);
                if (n15 == 0)
                    pbase[(size_t)(mt * 16 + kg * 4 + r) * NSLOT] = v;
            }
        }
    }
}

// ---------------- K4: inv_sum[b,q] — one block per (b,q), 2048-slot reduce ----
__global__ __launch_bounds__(256) void k_invsum(const float* __restrict__ partial,
                                                float* __restrict__ inv) {
    int blk = blockIdx.x;            // 0..1599
    int b = blk / QQ, qq = blk % QQ;
    const float* p = partial + ((size_t)b * QPAD + qq) * NSLOT;
    int t = threadIdx.x;
    float v = 0.0f;
#pragma unroll
    for (int j = 0; j < NSLOT / 256; ++j) v += p[t + j * 256];
#pragma unroll
    for (int off = 32; off; off >>= 1) v += __shfl_xor(v, off, 64);
    __shared__ float red[4];
    if ((t & 63) == 0) red[t >> 6] = v;
    __syncthreads();
    if (t == 0) inv[blk] = 1.0f / (red[0] + red[1] + red[2] + red[3]);
}

// ---------------- K5: write-pass (DIAGNOSTIC: reps) ---------------------------
__global__ __launch_bounds__(256) void k_write(const unsigned short* __restrict__ qphi,
                                               const unsigned short* __restrict__ qplo,
                                               const unsigned short* __restrict__ kpT,
                                               const int* __restrict__ mask,
                                               const float* __restrict__ inv,
                                               float* __restrict__ out,
                                               int reps) {
    int hws = blockIdx.x, n = blockIdx.y, b = blockIdx.z;
    int t = threadIdx.x, w = t >> 6, lane = t & 63;
    int n15 = lane & 15, kg = lane >> 4;
    int hw0 = hws * 256 + w * 64;
    float mm[4];
#pragma unroll
    for (int ht = 0; ht < 4; ++ht)
        mm[ht] = mask[b * HWN + hw0 + ht * 16 + n15] ? 0.0f : 1.0f;
    __shared__ float lt[4][16][68];
#pragma unroll 1
    for (int rep = 0; rep < reps; ++rep) {
        int off0 = 0; asm volatile("" : "+v"(off0));
        bf16x8_t bf[4];
#pragma unroll
        for (int ht = 0; ht < 4; ++ht)
            bf[ht] = *reinterpret_cast<const bf16x8_t*>(
                kpT + ((size_t)(b * HWN + hw0 + ht * 16 + n15)) * 256 + n * 32 + kg * 8 + off0);
        const unsigned short* ahi_b = qphi + ((size_t)(b * QPAD + n15)) * 256 + n * 32 + kg * 8 + off0;
        const unsigned short* alo_b = qplo + ((size_t)(b * QPAD + n15)) * 256 + n * 32 + kg * 8 + off0;
#pragma unroll 1
        for (int qt = 0; qt < 7; ++qt) {
            bf16x8_t ahi = *reinterpret_cast<const bf16x8_t*>(ahi_b + (size_t)(qt * 16) * 256);
            bf16x8_t alo = *reinterpret_cast<const bf16x8_t*>(alo_b + (size_t)(qt * 16) * 256);
            float invq[4];
#pragma unroll
            for (int r = 0; r < 4; ++r) {
                int qrow = qt * 16 + kg * 4 + r;
                invq[r] = (qrow < QQ) ? inv[b * QQ + qrow] : 0.0f;
            }
#pragma unroll
            for (int ht = 0; ht < 4; ++ht) {
                f32x4_t acc = {0.f, 0.f, 0.f, 0.f};
                acc = __builtin_amdgcn_mfma_f32_16x16x32_bf16(ahi, bf[ht], acc, 0, 0, 0);
                acc = __builtin_amdgcn_mfma_f32_16x16x32_bf16(alo, bf[ht], acc, 0, 0, 0);
#pragma unroll
                for (int r = 0; r < 4; ++r)
                    lt[w][kg * 4 + r][ht * 16 + n15] = __expf(acc[r]) * mm[ht] * invq[r];
            }
#pragma unroll
            for (int j = 0; j < 4; ++j) {
                int rr = j * 4 + kg;
                int qrow = qt * 16 + rr;
                f32x4_t v4 = *(const f32x4_t*)&lt[w][rr][n15 * 4];
                if (qrow < QQ)
                    *(f32x4_t*)(out + (((size_t)(b * QQ + qrow)) * NH + n) * HWN + hw0 + n15 * 4) = v4;
            }
        }
    }
}

extern "C" void kernel_launch(void* const* d_in, const int* in_sizes, int n_in,
                              void* d_out, int out_size, void* d_ws, size_t ws_size,
                              hipStream_t stream) {
    const float* q    = (const float*)d_in[0];
    const float* k    = (const float*)d_in[1];
    const float* Wq   = (const float*)d_in[2];
    const float* bq   = (const float*)d_in[3];
    const float* Wk   = (const float*)d_in[4];
    const float* bk   = (const float*)d_in[5];
    const int*   mask = (const int*)d_in[6];
    float* out = (float*)d_out;

    char* base = (char*)d_ws;
    unsigned short* kpT  = (unsigned short*)(base);              // 33,554,432 B
    unsigned short* qphi = (unsigned short*)(base + 33554432);   //    917,504 B
    unsigned short* qplo = (unsigned short*)(base + 34471936);   //    917,504 B
    float*  WqT     = (float*)(base + 35389440);                 //    262,144 B
    unsigned short* Wkbf = (unsigned short*)(base + 35651584);   //    131,072 B
    float*  partial = (float*)(base + 35782656);                 // 14,680,064 B
    float*  inv     = (float*)(base + 50462720);                 //      6,400 B
    if (ws_size < (size_t)50469120) return;

    k_prep  <<<dim3(512), dim3(256), 0, stream>>>(Wq, Wk, WqT, Wkbf);
    k_qproj <<<dim3(448), dim3(256), 0, stream>>>(q, WqT, bq, qphi, qplo);
    k_kproj3<<<dim3(64, 16), dim3(512), 0, stream>>>(k, Wkbf, bk, kpT, 4);
    k_sums  <<<dim3(64, 8, 16), dim3(256), 0, stream>>>(qphi, qplo, kpT, mask, partial, 6);
    k_invsum<<<dim3(1600), dim3(256), 0, stream>>>(partial, inv);
    k_write <<<dim3(16, 8, 16), dim3(256), 0, stream>>>(qphi, qplo, kpT, mask, inv, out, 3);
}

// Round 12
// 193.644 us; speedup vs baseline: 4.0570x; 4.0570x over previous
//
#include <hip/hip_runtime.h>
#include <hip/hip_bf16.h>
#include <math.h>

// Problem constants
#define BB 16
#define QQ 100
#define NH 8
#define HWN 4096
#define NORM_FACT 0.17677669529663687f   // 32^-0.5
#define QPAD 112        // q rows padded to 112 (7 tiles of 16)

typedef short bf16x8_t __attribute__((ext_vector_type(8)));
typedef float f32x4_t  __attribute__((ext_vector_type(4)));

__device__ __forceinline__ unsigned short bf16bits(float f) {
    __hip_bfloat16 h = __float2bfloat16(f);           // RNE
    return __builtin_bit_cast(unsigned short, h);
}
__device__ __forceinline__ float bf16tof(unsigned short u) {
    union { unsigned int i; float f; } x; x.i = (unsigned int)u << 16; return x.f;
}

// ---------------- K0: WqT (fp32 transpose) + Wk -> bf16 -----------------------
__global__ void k_prep(const float* __restrict__ Wq, const float* __restrict__ Wk,
                       float* __restrict__ WqT, unsigned short* __restrict__ Wkbf) {
    int idx = blockIdx.x;
    int h = threadIdx.x;
    if (idx < 256) {
        WqT[idx * 256 + h] = Wq[h * 256 + idx];
    } else {
        int r = idx - 256;
        Wkbf[r * 256 + h] = bf16bits(Wk[r * 256 + h]);
    }
}

// ---------------- K1: q-proj -> bf16 hi/lo split, padded to 112 rows ----------
__global__ __launch_bounds__(256) void k_qproj(const float* __restrict__ q,
                                               const float* __restrict__ WqT,
                                               const float* __restrict__ bq,
                                               unsigned short* __restrict__ qphi,
                                               unsigned short* __restrict__ qplo) {
    int blk = blockIdx.x;             // 16 b x 28 tiles of 4 rows
    int b = blk / 28, q0 = (blk % 28) * 4;
    int h = threadIdx.x;
    size_t obase = ((size_t)b * QPAD + q0) * 256 + h;
    if (q0 >= QQ) {                   // padding rows -> zeros
#pragma unroll
        for (int i = 0; i < 4; ++i) { qphi[obase + i * 256] = 0; qplo[obase + i * 256] = 0; }
        return;
    }
    __shared__ float qsh[4][256];
    int ibase = (b * QQ + q0) * 256;
#pragma unroll
    for (int i = 0; i < 4; ++i) qsh[i][h] = q[ibase + i * 256 + h];
    __syncthreads();
    float bias = bq[h];
    float a0 = bias, a1 = bias, a2 = bias, a3 = bias;
    for (int c = 0; c < 256; ++c) {
        float wv = WqT[c * 256 + h];
        a0 = fmaf(qsh[0][c], wv, a0);
        a1 = fmaf(qsh[1][c], wv, a1);
        a2 = fmaf(qsh[2][c], wv, a2);
        a3 = fmaf(qsh[3][c], wv, a3);
    }
    float a[4] = {a0 * NORM_FACT, a1 * NORM_FACT, a2 * NORM_FACT, a3 * NORM_FACT};
#pragma unroll
    for (int i = 0; i < 4; ++i) {
        unsigned short hi = bf16bits(a[i]);
        qphi[obase + i * 256] = hi;
        qplo[obase + i * 256] = bf16bits(a[i] - bf16tof(hi));
    }
}

// ---------------- K2: fused transpose+kproj (R10-verified, ~16-20 us) ---------
__global__ __launch_bounds__(512) void k_kproj3(const float* __restrict__ k,
                                                const unsigned short* __restrict__ Wkbf,
                                                const float* __restrict__ bk,
                                                unsigned short* __restrict__ kpT) {
    int b = blockIdx.y;
    int hwblk = blockIdx.x * 64;
    int t = threadIdx.x;
    int w = t >> 6, lane = t & 63;
    int hwt = w & 3, oh = w >> 2;          // wave -> (16-hw tile, 128-o half)
    int n15 = lane & 15, kg = lane >> 4;
    int hw_l = hwt * 16 + n15;

    __shared__ float lds_f[64][140];       // 35,840 B

    f32x4_t acc[8];
#pragma unroll
    for (int m = 0; m < 8; ++m) acc[m] = f32x4_t{0.f, 0.f, 0.f, 0.f};

    const float* kb = k + (size_t)b * 256 * HWN + hwblk;
    const unsigned short* wbase = Wkbf + ((size_t)(oh * 128 + n15)) * 256 + kg * 8;
    int c_l = t >> 4, l16 = t & 15;

#pragma unroll
    for (int chunk = 0; chunk < 2; ++chunk) {
#pragma unroll
        for (int p = 0; p < 4; ++p) {
            int cc = p * 32 + c_l;
            float4 v = *(const float4*)(kb + (size_t)(chunk * 128 + cc) * HWN + l16 * 4);
            lds_f[l16 * 4 + 0][cc] = v.x;
            lds_f[l16 * 4 + 1][cc] = v.y;
            lds_f[l16 * 4 + 2][cc] = v.z;
            lds_f[l16 * 4 + 3][cc] = v.w;
        }
        __syncthreads();
#pragma unroll
        for (int ksl = 0; ksl < 4; ++ksl) {
            f32x4_t f0 = *(const f32x4_t*)&lds_f[hw_l][ksl * 32 + kg * 8];
            f32x4_t f1 = *(const f32x4_t*)&lds_f[hw_l][ksl * 32 + kg * 8 + 4];
            bf16x8_t bfrag;
#pragma unroll
            for (int j = 0; j < 4; ++j) {
                bfrag[j]     = (short)bf16bits(f0[j]);
                bfrag[4 + j] = (short)bf16bits(f1[j]);
            }
            int ks = chunk * 4 + ksl;
#pragma unroll
            for (int m = 0; m < 8; ++m) {
                bf16x8_t afrag = *reinterpret_cast<const bf16x8_t*>(wbase + (size_t)m * 16 * 256 + ks * 32);
                acc[m] = __builtin_amdgcn_mfma_f32_16x16x32_bf16(afrag, bfrag, acc[m], 0, 0, 0);
            }
        }
        __syncthreads();
    }

    unsigned short* tile2 = (unsigned short*)lds_f;
#pragma unroll
    for (int m = 0; m < 8; ++m) {
        ushort4 pk;
        unsigned short* pkp = (unsigned short*)&pk;
#pragma unroll
        for (int r = 0; r < 4; ++r) {
            int o = oh * 128 + m * 16 + kg * 4 + r;
            pkp[r] = bf16bits(acc[m][r] + bk[o]);
        }
        *(ushort4*)&tile2[(size_t)hw_l * 264 + oh * 128 + m * 16 + kg * 4] = pk;
    }
    __syncthreads();
    int l5 = t & 31;
#pragma unroll
    for (int it = 0; it < 4; ++it) {
        int row = it * 16 + (t >> 5);
        uint4 v = *(const uint4*)&tile2[(size_t)row * 264 + l5 * 8];
        *(uint4*)(kpT + ((size_t)b * HWN + hwblk + row) * 256 + l5 * 8) = v;
    }
}

// ---------------- K3: sum-pass — ALL 8 heads per wave, ONE reduce at end ------
// grid (64 hwblocks of 64, 16 b); 4 waves; wave = one 16-hw tile x all heads
__global__ __launch_bounds__(256) void k_sums(const unsigned short* __restrict__ qphi,
                                              const unsigned short* __restrict__ qplo,
                                              const unsigned short* __restrict__ kpT,
                                              const int* __restrict__ mask,
                                              float* __restrict__ partial) {
    int hwb = blockIdx.x, b = blockIdx.y;
    int t = threadIdx.x, w = t >> 6, lane = t & 63;
    int n15 = lane & 15, kg = lane >> 4;
    int hw = hwb * 64 + w * 16 + n15;
    float mm = mask[b * HWN + hw] ? 0.0f : 1.0f;
    const unsigned short* brow  = kpT  + ((size_t)(b * HWN + hw)) * 256 + kg * 8;
    const unsigned short* ahi_b = qphi + ((size_t)(b * QPAD + n15)) * 256 + kg * 8;
    const unsigned short* alo_b = qplo + ((size_t)(b * QPAD + n15)) * 256 + kg * 8;
    float sums[7][4] = {};
#pragma unroll 1
    for (int n = 0; n < NH; ++n) {
        bf16x8_t bfr = *reinterpret_cast<const bf16x8_t*>(brow + n * 32);
#pragma unroll
        for (int mt = 0; mt < 7; ++mt) {
            bf16x8_t ahi = *reinterpret_cast<const bf16x8_t*>(ahi_b + (size_t)(mt * 16) * 256 + n * 32);
            bf16x8_t alo = *reinterpret_cast<const bf16x8_t*>(alo_b + (size_t)(mt * 16) * 256 + n * 32);
            f32x4_t a2 = {0.f, 0.f, 0.f, 0.f};
            a2 = __builtin_amdgcn_mfma_f32_16x16x32_bf16(ahi, bfr, a2, 0, 0, 0);
            a2 = __builtin_amdgcn_mfma_f32_16x16x32_bf16(alo, bfr, a2, 0, 0, 0);
#pragma unroll
            for (int r = 0; r < 4; ++r)
                sums[mt][r] += __expf(a2[r]) * mm;
        }
    }
#pragma unroll
    for (int mt = 0; mt < 7; ++mt)
#pragma unroll
        for (int r = 0; r < 4; ++r) {
            float v = sums[mt][r];
            v += __shfl_xor(v, 1, 64);
            v += __shfl_xor(v, 2, 64);
            v += __shfl_xor(v, 4, 64);
            v += __shfl_xor(v, 8, 64);
            if (n15 == 0) {
                int qrow = mt * 16 + kg * 4 + r;
                partial[((size_t)b * QPAD + qrow) * 256 + hwb * 4 + w] = v;
            }
        }
}

// ---------------- K4: inv_sum[b,q] — one block per (b,q), 256-slot reduce -----
__global__ __launch_bounds__(256) void k_invsum(const float* __restrict__ partial,
                                                float* __restrict__ inv) {
    int blk = blockIdx.x;            // 0..1599
    int b = blk / QQ, qq = blk % QQ;
    const float* p = partial + ((size_t)b * QPAD + qq) * 256;
    int t = threadIdx.x;
    float v = p[t];
#pragma unroll
    for (int off = 32; off; off >>= 1) v += __shfl_xor(v, off, 64);
    __shared__ float red[4];
    if ((t & 63) == 0) red[t >> 6] = v;
    __syncthreads();
    if (t == 0) inv[blk] = 1.0f / (red[0] + red[1] + red[2] + red[3]);
}

// ---------------- K5: write-pass — block-staged, 1KB full-wave row stores -----
// grid (16 hw strips of 256, 8 heads, 16 b); 4 waves compute the SAME qt tile
// (each wave a 64-hw slice), then cooperatively store 16 rows x 1KB contiguous.
__global__ __launch_bounds__(256) void k_write(const unsigned short* __restrict__ qphi,
                                               const unsigned short* __restrict__ qplo,
                                               const unsigned short* __restrict__ kpT,
                                               const int* __restrict__ mask,
                                               const float* __restrict__ inv,
                                               float* __restrict__ out) {
    int hws = blockIdx.x, n = blockIdx.y, b = blockIdx.z;
    int t = threadIdx.x, w = t >> 6, lane = t & 63;
    int n15 = lane & 15, kg = lane >> 4;
    int hw0 = hws * 256 + w * 64;
    float mm[4];
#pragma unroll
    for (int ht = 0; ht < 4; ++ht)
        mm[ht] = mask[b * HWN + hw0 + ht * 16 + n15] ? 0.0f : 1.0f;
    bf16x8_t bf[4];
#pragma unroll
    for (int ht = 0; ht < 4; ++ht)
        bf[ht] = *reinterpret_cast<const bf16x8_t*>(
            kpT + ((size_t)(b * HWN + hw0 + ht * 16 + n15)) * 256 + n * 32 + kg * 8);
    const unsigned short* ahi_b = qphi + ((size_t)(b * QPAD + n15)) * 256 + n * 32 + kg * 8;
    const unsigned short* alo_b = qplo + ((size_t)(b * QPAD + n15)) * 256 + n * 32 + kg * 8;
    __shared__ float lt[16][260];     // block-shared 16q x 256hw staging (16.6 KB)
#pragma unroll 1
    for (int qt = 0; qt < 7; ++qt) {
        bf16x8_t ahi = *reinterpret_cast<const bf16x8_t*>(ahi_b + (size_t)(qt * 16) * 256);
        bf16x8_t alo = *reinterpret_cast<const bf16x8_t*>(alo_b + (size_t)(qt * 16) * 256);
        float invq[4];
#pragma unroll
        for (int r = 0; r < 4; ++r) {
            int qrow = qt * 16 + kg * 4 + r;
            invq[r] = (qrow < QQ) ? inv[b * QQ + qrow] : 0.0f;
        }
#pragma unroll
        for (int ht = 0; ht < 4; ++ht) {
            f32x4_t acc = {0.f, 0.f, 0.f, 0.f};
            acc = __builtin_amdgcn_mfma_f32_16x16x32_bf16(ahi, bf[ht], acc, 0, 0, 0);
            acc = __builtin_amdgcn_mfma_f32_16x16x32_bf16(alo, bf[ht], acc, 0, 0, 0);
#pragma unroll
            for (int r = 0; r < 4; ++r)
                lt[kg * 4 + r][w * 64 + ht * 16 + n15] = __expf(acc[r]) * mm[ht] * invq[r];
        }
        __syncthreads();
        // cooperative store: full wave emits one 1KB contiguous row segment
#pragma unroll
        for (int j = 0; j < 4; ++j) {
            int row = w * 4 + j;
            int qrow = qt * 16 + row;
            f32x4_t v4 = *(const f32x4_t*)&lt[row][lane * 4];
            if (qrow < QQ)
                __builtin_nontemporal_store(v4,
                    (f32x4_t*)(out + (((size_t)(b * QQ + qrow)) * NH + n) * HWN + hws * 256 + lane * 4));
        }
        __syncthreads();
    }
}

extern "C" void kernel_launch(void* const* d_in, const int* in_sizes, int n_in,
                              void* d_out, int out_size, void* d_ws, size_t ws_size,
                              hipStream_t stream) {
    const float* q    = (const float*)d_in[0];
    const float* k    = (const float*)d_in[1];
    const float* Wq   = (const float*)d_in[2];
    const float* bq   = (const float*)d_in[3];
    const float* Wk   = (const float*)d_in[4];
    const float* bk   = (const float*)d_in[5];
    const int*   mask = (const int*)d_in[6];
    float* out = (float*)d_out;

    char* base = (char*)d_ws;
    unsigned short* kpT  = (unsigned short*)(base);              // 33,554,432 B
    unsigned short* qphi = (unsigned short*)(base + 33554432);   //    917,504 B
    unsigned short* qplo = (unsigned short*)(base + 34471936);   //    917,504 B
    float*  WqT     = (float*)(base + 35389440);                 //    262,144 B
    unsigned short* Wkbf = (unsigned short*)(base + 35651584);   //    131,072 B
    float*  partial = (float*)(base + 35782656);                 //  1,835,008 B
    float*  inv     = (float*)(base + 37617664);                 //      6,400 B
    if (ws_size < (size_t)37624064) return;

    k_prep  <<<dim3(512), dim3(256), 0, stream>>>(Wq, Wk, WqT, Wkbf);
    k_qproj <<<dim3(448), dim3(256), 0, stream>>>(q, WqT, bq, qphi, qplo);
    k_kproj3<<<dim3(64, 16), dim3(512), 0, stream>>>(k, Wkbf, bk, kpT);
    k_sums  <<<dim3(64, 16), dim3(256), 0, stream>>>(qphi, qplo, kpT, mask, partial);
    k_invsum<<<dim3(1600), dim3(256), 0, stream>>>(partial, inv);
    k_write <<<dim3(16, 8, 16), dim3(256), 0, stream>>>(qphi, qplo, kpT, mask, inv, out);
}

// Round 14
// 192.930 us; speedup vs baseline: 4.0720x; 1.0037x over previous
//
#include <hip/hip_runtime.h>
#include <hip/hip_bf16.h>
#include <math.h>

// Problem constants
#define BB 16
#define QQ 100
#define NH 8
#define HWN 4096
#define NORM_FACT 0.17677669529663687f   // 32^-0.5
#define QPAD 112        // q rows padded to 112 (7 tiles of 16)

typedef short bf16x8_t __attribute__((ext_vector_type(8)));
typedef float f32x4_t  __attribute__((ext_vector_type(4)));

__device__ __forceinline__ unsigned short bf16bits(float f) {
    __hip_bfloat16 h = __float2bfloat16(f);           // RNE
    return __builtin_bit_cast(unsigned short, h);
}
__device__ __forceinline__ float bf16tof(unsigned short u) {
    union { unsigned int i; float f; } x; x.i = (unsigned int)u << 16; return x.f;
}

// ---------------- K0: WqT (fp32 transpose) + Wk -> bf16 -----------------------
__global__ void k_prep(const float* __restrict__ Wq, const float* __restrict__ Wk,
                       float* __restrict__ WqT, unsigned short* __restrict__ Wkbf) {
    int idx = blockIdx.x;
    int h = threadIdx.x;
    if (idx < 256) {
        WqT[idx * 256 + h] = Wq[h * 256 + idx];
    } else {
        int r = idx - 256;
        Wkbf[r * 256 + h] = bf16bits(Wk[r * 256 + h]);
    }
}

// ---------------- K1: q-proj -> bf16 hi/lo split, padded to 112 rows ----------
__global__ __launch_bounds__(256) void k_qproj(const float* __restrict__ q,
                                               const float* __restrict__ WqT,
                                               const float* __restrict__ bq,
                                               unsigned short* __restrict__ qphi,
                                               unsigned short* __restrict__ qplo) {
    int blk = blockIdx.x;             // 16 b x 28 tiles of 4 rows
    int b = blk / 28, q0 = (blk % 28) * 4;
    int h = threadIdx.x;
    size_t obase = ((size_t)b * QPAD + q0) * 256 + h;
    if (q0 >= QQ) {                   // padding rows -> zeros
#pragma unroll
        for (int i = 0; i < 4; ++i) { qphi[obase + i * 256] = 0; qplo[obase + i * 256] = 0; }
        return;
    }
    __shared__ float qsh[4][256];
    int ibase = (b * QQ + q0) * 256;
#pragma unroll
    for (int i = 0; i < 4; ++i) qsh[i][h] = q[ibase + i * 256 + h];
    __syncthreads();
    float bias = bq[h];
    float a0 = bias, a1 = bias, a2 = bias, a3 = bias;
    for (int c = 0; c < 256; ++c) {
        float wv = WqT[c * 256 + h];
        a0 = fmaf(qsh[0][c], wv, a0);
        a1 = fmaf(qsh[1][c], wv, a1);
        a2 = fmaf(qsh[2][c], wv, a2);
        a3 = fmaf(qsh[3][c], wv, a3);
    }
    float a[4] = {a0 * NORM_FACT, a1 * NORM_FACT, a2 * NORM_FACT, a3 * NORM_FACT};
#pragma unroll
    for (int i = 0; i < 4; ++i) {
        unsigned short hi = bf16bits(a[i]);
        qphi[obase + i * 256] = hi;
        qplo[obase + i * 256] = bf16bits(a[i] - bf16tof(hi));
    }
}

// ---------------- K2: fused transpose+kproj (R10-verified, ~18 us) ------------
__global__ __launch_bounds__(512) void k_kproj3(const float* __restrict__ k,
                                                const unsigned short* __restrict__ Wkbf,
                                                const float* __restrict__ bk,
                                                unsigned short* __restrict__ kpT) {
    int b = blockIdx.y;
    int hwblk = blockIdx.x * 64;
    int t = threadIdx.x;
    int w = t >> 6, lane = t & 63;
    int hwt = w & 3, oh = w >> 2;          // wave -> (16-hw tile, 128-o half)
    int n15 = lane & 15, kg = lane >> 4;
    int hw_l = hwt * 16 + n15;

    __shared__ float lds_f[64][140];       // 35,840 B

    f32x4_t acc[8];
#pragma unroll
    for (int m = 0; m < 8; ++m) acc[m] = f32x4_t{0.f, 0.f, 0.f, 0.f};

    const float* kb = k + (size_t)b * 256 * HWN + hwblk;
    const unsigned short* wbase = Wkbf + ((size_t)(oh * 128 + n15)) * 256 + kg * 8;
    int c_l = t >> 4, l16 = t & 15;

#pragma unroll
    for (int chunk = 0; chunk < 2; ++chunk) {
#pragma unroll
        for (int p = 0; p < 4; ++p) {
            int cc = p * 32 + c_l;
            float4 v = *(const float4*)(kb + (size_t)(chunk * 128 + cc) * HWN + l16 * 4);
            lds_f[l16 * 4 + 0][cc] = v.x;
            lds_f[l16 * 4 + 1][cc] = v.y;
            lds_f[l16 * 4 + 2][cc] = v.z;
            lds_f[l16 * 4 + 3][cc] = v.w;
        }
        __syncthreads();
#pragma unroll
        for (int ksl = 0; ksl < 4; ++ksl) {
            f32x4_t f0 = *(const f32x4_t*)&lds_f[hw_l][ksl * 32 + kg * 8];
            f32x4_t f1 = *(const f32x4_t*)&lds_f[hw_l][ksl * 32 + kg * 8 + 4];
            bf16x8_t bfrag;
#pragma unroll
            for (int j = 0; j < 4; ++j) {
                bfrag[j]     = (short)bf16bits(f0[j]);
                bfrag[4 + j] = (short)bf16bits(f1[j]);
            }
            int ks = chunk * 4 + ksl;
#pragma unroll
            for (int m = 0; m < 8; ++m) {
                bf16x8_t afrag = *reinterpret_cast<const bf16x8_t*>(wbase + (size_t)m * 16 * 256 + ks * 32);
                acc[m] = __builtin_amdgcn_mfma_f32_16x16x32_bf16(afrag, bfrag, acc[m], 0, 0, 0);
            }
        }
        __syncthreads();
    }

    unsigned short* tile2 = (unsigned short*)lds_f;
#pragma unroll
    for (int m = 0; m < 8; ++m) {
        ushort4 pk;
        unsigned short* pkp = (unsigned short*)&pk;
#pragma unroll
        for (int r = 0; r < 4; ++r) {
            int o = oh * 128 + m * 16 + kg * 4 + r;
            pkp[r] = bf16bits(acc[m][r] + bk[o]);
        }
        *(ushort4*)&tile2[(size_t)hw_l * 264 + oh * 128 + m * 16 + kg * 4] = pk;
    }
    __syncthreads();
    int l5 = t & 31;
#pragma unroll
    for (int it = 0; it < 4; ++it) {
        int row = it * 16 + (t >> 5);
        uint4 v = *(const uint4*)&tile2[(size_t)row * 264 + l5 * 8];
        *(uint4*)(kpT + ((size_t)b * HWN + hwblk + row) * 256 + l5 * 8) = v;
    }
}

// ---------------- K3: sum-pass — A staged in LDS per block, LDS reduce --------
// grid (64 hwb of 64, 16 b); 4 waves; wave = one 16-hw tile, all heads/q.
// FIX vs R13: stage 32 B/thread/array (2x uint4) -> full row coverage.
__global__ __launch_bounds__(256) void k_sums(const unsigned short* __restrict__ qphi,
                                              const unsigned short* __restrict__ qplo,
                                              const unsigned short* __restrict__ kpT,
                                              const int* __restrict__ mask,
                                              float* __restrict__ partial) {
    int hwb = blockIdx.x, b = blockIdx.y;
    int t = threadIdx.x, w = t >> 6, lane = t & 63;
    int n15 = lane & 15, kg = lane >> 4;
    int hw = hwb * 64 + w * 16 + n15;
    float mm = mask[b * HWN + hw] ? 0.0f : 1.0f;

    __shared__ float ldsbuf[8960];                 // 35,840 B (stage + reduce overlay)
    unsigned short* sA = (unsigned short*)ldsbuf;  // stage: qphi[16][264] | qplo[16][264]

    // preload all 8 kpT B-frags for this lane's hw row (32 VGPR)
    const unsigned short* brow = kpT + ((size_t)(b * HWN + hw)) * 256 + kg * 8;
    bf16x8_t bfr[8];
#pragma unroll
    for (int n = 0; n < NH; ++n)
        bfr[n] = *reinterpret_cast<const bf16x8_t*>(brow + n * 32);

    const unsigned short* ghi = qphi + (size_t)b * QPAD * 256;
    const unsigned short* glo = qplo + (size_t)b * QPAD * 256;
    int srow = t >> 4, schunk = t & 15;            // stage role: row 0..15, 32B chunk

    float sums[7][4] = {};
#pragma unroll 1
    for (int mt = 0; mt < 7; ++mt) {
        // stage 16 q-rows of qphi+qplo into LDS: 2x uint4 (32B) per thread per array
        const unsigned short* shi = ghi + (size_t)(mt * 16 + srow) * 256 + schunk * 16;
        const unsigned short* slo = glo + (size_t)(mt * 16 + srow) * 256 + schunk * 16;
        uint4 vhi0 = *(const uint4*)(shi);
        uint4 vhi1 = *(const uint4*)(shi + 8);
        uint4 vlo0 = *(const uint4*)(slo);
        uint4 vlo1 = *(const uint4*)(slo + 8);
        *(uint4*)&sA[srow * 264 + schunk * 16]          = vhi0;
        *(uint4*)&sA[srow * 264 + schunk * 16 + 8]      = vhi1;
        *(uint4*)&sA[16 * 264 + srow * 264 + schunk * 16]     = vlo0;
        *(uint4*)&sA[16 * 264 + srow * 264 + schunk * 16 + 8] = vlo1;
        __syncthreads();
#pragma unroll
        for (int n = 0; n < NH; ++n) {
            bf16x8_t ahi = *reinterpret_cast<const bf16x8_t*>(&sA[n15 * 264 + n * 32 + kg * 8]);
            bf16x8_t alo = *reinterpret_cast<const bf16x8_t*>(&sA[16 * 264 + n15 * 264 + n * 32 + kg * 8]);
            f32x4_t a2 = {0.f, 0.f, 0.f, 0.f};
            a2 = __builtin_amdgcn_mfma_f32_16x16x32_bf16(ahi, bfr[n], a2, 0, 0, 0);
            a2 = __builtin_amdgcn_mfma_f32_16x16x32_bf16(alo, bfr[n], a2, 0, 0, 0);
#pragma unroll
            for (int r = 0; r < 4; ++r)
                sums[mt][r] += __expf(a2[r]) * mm;
        }
        __syncthreads();   // all reads done before next stage overwrite / reduce overlay
    }

    // per-wave LDS reduce: region [w][112 rows][20] floats (overlays stage buffer)
    float* R = ldsbuf + w * 112 * 20;
#pragma unroll
    for (int mt = 0; mt < 7; ++mt)
#pragma unroll
        for (int r = 0; r < 4; ++r)
            R[(mt * 16 + kg * 4 + r) * 20 + n15] = sums[mt][r];
    // same-wave LDS RAW (DS ops issue in order within a wave) -> no barrier
    if (lane < 56) {
#pragma unroll
        for (int p = 0; p < 2; ++p) {
            int row = lane + p * 56;
            f32x4_t v0 = *(const f32x4_t*)&R[row * 20 + 0];
            f32x4_t v1 = *(const f32x4_t*)&R[row * 20 + 4];
            f32x4_t v2 = *(const f32x4_t*)&R[row * 20 + 8];
            f32x4_t v3 = *(const f32x4_t*)&R[row * 20 + 12];
            float s = (v0[0]+v0[1]+v0[2]+v0[3]) + (v1[0]+v1[1]+v1[2]+v1[3])
                    + (v2[0]+v2[1]+v2[2]+v2[3]) + (v3[0]+v3[1]+v3[2]+v3[3]);
            partial[((size_t)b * QPAD + row) * 256 + hwb * 4 + w] = s;
        }
    }
}

// ---------------- K4: inv_sum[b,q] — one block per (b,q), 256-slot reduce -----
__global__ __launch_bounds__(256) void k_invsum(const float* __restrict__ partial,
                                                float* __restrict__ inv) {
    int blk = blockIdx.x;            // 0..1599
    int b = blk / QQ, qq = blk % QQ;
    const float* p = partial + ((size_t)b * QPAD + qq) * 256;
    int t = threadIdx.x;
    float v = p[t];
#pragma unroll
    for (int off = 32; off; off >>= 1) v += __shfl_xor(v, off, 64);
    __shared__ float red[4];
    if ((t & 63) == 0) red[t >> 6] = v;
    __syncthreads();
    if (t == 0) inv[blk] = 1.0f / (red[0] + red[1] + red[2] + red[3]);
}

// ---------------- K5: write-pass — hws-inner, 16KB sequential row streams -----
// grid (7 qt, 8 n, 16 b); 4 waves; block owns 16 q rows x full 4096 hw for one n.
__global__ __launch_bounds__(256) void k_write(const unsigned short* __restrict__ qphi,
                                               const unsigned short* __restrict__ qplo,
                                               const unsigned short* __restrict__ kpT,
                                               const int* __restrict__ mask,
                                               const float* __restrict__ inv,
                                               float* __restrict__ out) {
    int qt = blockIdx.x, n = blockIdx.y, b = blockIdx.z;
    int t = threadIdx.x, w = t >> 6, lane = t & 63;
    int n15 = lane & 15, kg = lane >> 4;

    // per-block constants: A-frags + inv (loaded once)
    bf16x8_t ahi = *reinterpret_cast<const bf16x8_t*>(
        qphi + ((size_t)(b * QPAD + qt * 16 + n15)) * 256 + n * 32 + kg * 8);
    bf16x8_t alo = *reinterpret_cast<const bf16x8_t*>(
        qplo + ((size_t)(b * QPAD + qt * 16 + n15)) * 256 + n * 32 + kg * 8);
    float invq[4];
#pragma unroll
    for (int r = 0; r < 4; ++r) {
        int qrow = qt * 16 + kg * 4 + r;
        invq[r] = (qrow < QQ) ? inv[b * QQ + qrow] : 0.0f;
    }

    __shared__ float lt[16][260];     // block staging: 16q x 256hw (16.6 KB)

    // software pipeline: preload hws=0 B-frags + mask
    bf16x8_t bc[4], bn[4];
    float mc[4], mn[4];
#pragma unroll
    for (int ht = 0; ht < 4; ++ht) {
        int hw = w * 64 + ht * 16 + n15;
        bc[ht] = *reinterpret_cast<const bf16x8_t*>(
            kpT + ((size_t)(b * HWN + hw)) * 256 + n * 32 + kg * 8);
        mc[ht] = mask[b * HWN + hw] ? 0.0f : 1.0f;
        bn[ht] = bc[ht];
        mn[ht] = mc[ht];
    }

#pragma unroll 1
    for (int hws = 0; hws < 16; ++hws) {
        if (hws < 15) {
#pragma unroll
            for (int ht = 0; ht < 4; ++ht) {
                int hw = (hws + 1) * 256 + w * 64 + ht * 16 + n15;
                bn[ht] = *reinterpret_cast<const bf16x8_t*>(
                    kpT + ((size_t)(b * HWN + hw)) * 256 + n * 32 + kg * 8);
                mn[ht] = mask[b * HWN + hw] ? 0.0f : 1.0f;
            }
        }
#pragma unroll
        for (int ht = 0; ht < 4; ++ht) {
            f32x4_t acc = {0.f, 0.f, 0.f, 0.f};
            acc = __builtin_amdgcn_mfma_f32_16x16x32_bf16(ahi, bc[ht], acc, 0, 0, 0);
            acc = __builtin_amdgcn_mfma_f32_16x16x32_bf16(alo, bc[ht], acc, 0, 0, 0);
#pragma unroll
            for (int r = 0; r < 4; ++r)
                lt[kg * 4 + r][w * 64 + ht * 16 + n15] = __expf(acc[r]) * mc[ht] * invq[r];
        }
        __syncthreads();
        // cooperative store: wave w emits rows w*4..w*4+3, 1KB contiguous each
#pragma unroll
        for (int j = 0; j < 4; ++j) {
            int row = w * 4 + j;
            int qrow = qt * 16 + row;
            f32x4_t v4 = *(const f32x4_t*)&lt[row][lane * 4];
            if (qrow < QQ)
                __builtin_nontemporal_store(v4,
                    (f32x4_t*)(out + (((size_t)(b * QQ + qrow)) * NH + n) * HWN + hws * 256 + lane * 4));
        }
        __syncthreads();
#pragma unroll
        for (int ht = 0; ht < 4; ++ht) { bc[ht] = bn[ht]; mc[ht] = mn[ht]; }
    }
}

extern "C" void kernel_launch(void* const* d_in, const int* in_sizes, int n_in,
                              void* d_out, int out_size, void* d_ws, size_t ws_size,
                              hipStream_t stream) {
    const float* q    = (const float*)d_in[0];
    const float* k    = (const float*)d_in[1];
    const float* Wq   = (const float*)d_in[2];
    const float* bq   = (const float*)d_in[3];
    const float* Wk   = (const float*)d_in[4];
    const float* bk   = (const float*)d_in[5];
    const int*   mask = (const int*)d_in[6];
    float* out = (float*)d_out;

    char* base = (char*)d_ws;
    unsigned short* kpT  = (unsigned short*)(base);              // 33,554,432 B
    unsigned short* qphi = (unsigned short*)(base + 33554432);   //    917,504 B
    unsigned short* qplo = (unsigned short*)(base + 34471936);   //    917,504 B
    float*  WqT     = (float*)(base + 35389440);                 //    262,144 B
    unsigned short* Wkbf = (unsigned short*)(base + 35651584);   //    131,072 B
    float*  partial = (float*)(base + 35782656);                 //  1,835,008 B
    float*  inv     = (float*)(base + 37617664);                 //      6,400 B
    if (ws_size < (size_t)37624064) return;

    k_prep  <<<dim3(512), dim3(256), 0, stream>>>(Wq, Wk, WqT, Wkbf);
    k_qproj <<<dim3(448), dim3(256), 0, stream>>>(q, WqT, bq, qphi, qplo);
    k_kproj3<<<dim3(64, 16), dim3(512), 0, stream>>>(k, Wkbf, bk, kpT);
    k_sums  <<<dim3(64, 16), dim3(256), 0, stream>>>(qphi, qplo, kpT, mask, partial);
    k_invsum<<<dim3(1600), dim3(256), 0, stream>>>(partial, inv);
    k_write <<<dim3(7, 8, 16), dim3(256), 0, stream>>>(qphi, qplo, kpT, mask, inv, out);
}